// Round 3
// baseline (323.826 us; speedup 1.0000x reference)
//
#include <hip/hip_runtime.h>
#include <hip/hip_bf16.h>

#define N_NODES 50000
#define N_EDGES 1600000
#define N_GRAPHS 512
#define VOCAB 1000
#define EMB 32
#define HID 64
#define N_CLASS 2

#define MAXDEG 96                      // Poisson(32) tail @96 ~ 4e-20/node

// ---- atomic-free CSR build (counting bucket-sort) ----
#define NVEC (N_EDGES / 4)             // 400000 int4 vectors
#define SORT_VPB 1024                  // vectors per block (256 thr x 4)
#define SORT_BLOCKS ((NVEC + SORT_VPB - 1) / SORT_VPB)   // 391
#define BSHIFT 9
#define BUCKET_NODES 512
#define NBUCK ((N_NODES + BUCKET_NODES - 1) / BUCKET_NODES)  // 98

#define L2P_BLOCKS 768                 // 3 blocks/CU co-resident
#define L2P_WAVES (L2P_BLOCKS * 4)     // 3072
#define L2P_CHUNK ((N_NODES + L2P_WAVES - 1) / L2P_WAVES)  // 17

typedef int iv4 __attribute__((ext_vector_type(4)));
typedef unsigned long long u64;

__device__ __forceinline__ float rdlane(float v, int k) {
    return __int_as_float(__builtin_amdgcn_readlane(__float_as_int(v), k));
}

// ---------------- K1: per-block bucket histogram (LDS atomics only) ----------------
__global__ __launch_bounds__(256) void hist_kernel(const int* __restrict__ dst,
                                                   int* __restrict__ hist) {
    __shared__ int lh[NBUCK];
    for (int b = threadIdx.x; b < NBUCK; b += 256) lh[b] = 0;
    __syncthreads();
    const iv4* dst4 = (const iv4*)dst;
    int vbase = blockIdx.x * SORT_VPB;
    #pragma unroll
    for (int t = 0; t < 4; ++t) {
        int v = vbase + t * 256 + threadIdx.x;
        if (v < NVEC) {
            iv4 d4 = __builtin_nontemporal_load(&dst4[v]);
            atomicAdd(&lh[d4.x >> BSHIFT], 1);
            atomicAdd(&lh[d4.y >> BSHIFT], 1);
            atomicAdd(&lh[d4.z >> BSHIFT], 1);
            atomicAdd(&lh[d4.w >> BSHIFT], 1);
        }
    }
    __syncthreads();
    for (int b = threadIdx.x; b < NBUCK; b += 256)
        hist[b * SORT_BLOCKS + blockIdx.x] = lh[b];
}

// ---------------- K2: exclusive scan of hist[NBUCK*SORT_BLOCKS], single block ----------------
__global__ __launch_bounds__(256) void scan_hist_kernel(int* __restrict__ hist) {
    const int total = NBUCK * SORT_BLOCKS;
    __shared__ int wsum[4];
    int tid = threadIdx.x;
    int lane = tid & 63, w = tid >> 6;
    int carry = 0;
    for (int base = 0; base < total; base += 256) {
        int idx = base + tid;
        int v = (idx < total) ? hist[idx] : 0;
        int inc = v;
        #pragma unroll
        for (int off = 1; off < 64; off <<= 1) {
            int n = __shfl_up(inc, off, 64);
            if (lane >= off) inc += n;
        }
        if (lane == 63) wsum[w] = inc;
        __syncthreads();
        int woff = 0;
        #pragma unroll
        for (int k = 0; k < 4; ++k) if (k < w) woff += wsum[k];
        if (idx < total) hist[idx] = carry + woff + inc - v;
        carry += wsum[0] + wsum[1] + wsum[2] + wsum[3];
        __syncthreads();
    }
}

// ---------------- K3: scatter edges into dense bucket-grouped buffer ----------------
// ebuf[pos] = (dst << 32) | (cls << 16) | src  ; pos from scanned base + LDS counter
__global__ __launch_bounds__(256) void scatter_kernel(const int* __restrict__ src,
        const int* __restrict__ dst, const int* __restrict__ x_ids,
        const int* __restrict__ hist, u64* __restrict__ ebuf) {
    __shared__ int lbase[NBUCK];
    for (int b = threadIdx.x; b < NBUCK; b += 256)
        lbase[b] = hist[b * SORT_BLOCKS + blockIdx.x];
    __syncthreads();
    const iv4* dst4 = (const iv4*)dst;
    const iv4* src4 = (const iv4*)src;
    int vbase = blockIdx.x * SORT_VPB;
    #pragma unroll
    for (int t = 0; t < 4; ++t) {
        int v = vbase + t * 256 + threadIdx.x;
        if (v < NVEC) {
            iv4 d4 = __builtin_nontemporal_load(&dst4[v]);
            iv4 s4 = __builtin_nontemporal_load(&src4[v]);
            // phase 1: payload gathers (independent)
            int pay0 = (x_ids[s4.x] << 16) | s4.x;
            int pay1 = (x_ids[s4.y] << 16) | s4.y;
            int pay2 = (x_ids[s4.z] << 16) | s4.z;
            int pay3 = (x_ids[s4.w] << 16) | s4.w;
            // phase 2: LDS slot allocation (fast, per-CU)
            int p0 = atomicAdd(&lbase[d4.x >> BSHIFT], 1);
            int p1 = atomicAdd(&lbase[d4.y >> BSHIFT], 1);
            int p2 = atomicAdd(&lbase[d4.z >> BSHIFT], 1);
            int p3 = atomicAdd(&lbase[d4.w >> BSHIFT], 1);
            // phase 3: clustered 8B stores (bucket regions advance monotonically)
            ebuf[p0] = ((u64)(unsigned)d4.x << 32) | (unsigned)pay0;
            ebuf[p1] = ((u64)(unsigned)d4.y << 32) | (unsigned)pay1;
            ebuf[p2] = ((u64)(unsigned)d4.z << 32) | (unsigned)pay2;
            ebuf[p3] = ((u64)(unsigned)d4.w << 32) | (unsigned)pay3;
        }
    }
}

// ---------------- K4: per-bucket CSR build (LDS cursors, L2-local stores) ----------------
__global__ __launch_bounds__(256) void csr_bucket_kernel(const u64* __restrict__ ebuf,
        const int* __restrict__ hist, int* __restrict__ cursor, int* __restrict__ csr) {
    int b = blockIdx.x;
    __shared__ int cur[BUCKET_NODES];
    for (int r = threadIdx.x; r < BUCKET_NODES; r += 256) cur[r] = 0;
    __syncthreads();
    int base = hist[b * SORT_BLOCKS];
    int end  = (b + 1 < NBUCK) ? hist[(b + 1) * SORT_BLOCKS] : N_EDGES;
    int node0 = b << BSHIFT;
    for (int i = base + threadIdx.x; i < end; i += 256) {
        u64 e = ebuf[i];                       // coalesced read
        int d = (int)(e >> 32);
        int pay = (int)(e & 0xffffffffu);
        int pos = atomicAdd(&cur[d - node0], 1);   // LDS atomic
        csr[d * MAXDEG + pos] = pay;               // store within 196KB slab
    }
    __syncthreads();
    for (int r = threadIdx.x; r < BUCKET_NODES; r += 256) {
        int d = node0 + r;
        if (d < N_NODES) cursor[d] = cur[r];
    }
}

// ---------------- precompute folded layer-1 tables ----------------
// e1b = bf16(embed @ w1l)  (VOCAB x HID), e1r = embed @ w1r (fp32)
__global__ void precompute_e1_kernel(const float* __restrict__ embed,
                                     const float* __restrict__ w1l,
                                     const float* __restrict__ w1r,
                                     __hip_bfloat16* __restrict__ e1b,
                                     float* __restrict__ e1r) {
    int id = blockIdx.x * blockDim.x + threadIdx.x;
    if (id >= VOCAB * HID) return;
    int v = id >> 6, j = id & 63;
    float a = 0.0f, b = 0.0f;
    #pragma unroll
    for (int k = 0; k < EMB; ++k) {
        float ev = embed[v * EMB + k];
        a = fmaf(ev, w1l[k * HID + j], a);
        b = fmaf(ev, w1r[k * HID + j], b);
    }
    e1b[id] = __float2bfloat16(a);
    e1r[id] = b;
}

// ---------------- layer 1: agg (bf16 class-table gather) + linear + relu ----------------
__global__ __launch_bounds__(256) void agg1_lin1_kernel(
        const int* __restrict__ x_ids, const int* __restrict__ csr,
        const int* __restrict__ deg_arr, const __hip_bfloat16* __restrict__ e1b,
        const float* __restrict__ e1r, const float* __restrict__ b1,
        float* __restrict__ h1, __hip_bfloat16* __restrict__ h1b) {
    int id = blockIdx.x * blockDim.x + threadIdx.x;
    int i = __builtin_amdgcn_readfirstlane(id >> 6);
    int j = threadIdx.x & 63;
    int s = i * MAXDEG;
    int deg = deg_arr[i];
    int e = s + deg;
    float s0 = 0.f, s1 = 0.f, s2 = 0.f, s3 = 0.f;
    float s4 = 0.f, s5 = 0.f, s6 = 0.f, s7 = 0.f;
    int k = s;
    for (; k + 8 <= e; k += 8) {
        int c0 = csr[k]     >> 16, c1 = csr[k + 1] >> 16;
        int c2 = csr[k + 2] >> 16, c3 = csr[k + 3] >> 16;
        int c4 = csr[k + 4] >> 16, c5 = csr[k + 5] >> 16;
        int c6 = csr[k + 6] >> 16, c7 = csr[k + 7] >> 16;
        s0 += (float)e1b[c0 * HID + j];
        s1 += (float)e1b[c1 * HID + j];
        s2 += (float)e1b[c2 * HID + j];
        s3 += (float)e1b[c3 * HID + j];
        s4 += (float)e1b[c4 * HID + j];
        s5 += (float)e1b[c5 * HID + j];
        s6 += (float)e1b[c6 * HID + j];
        s7 += (float)e1b[c7 * HID + j];
    }
    for (; k < e; ++k) s0 += (float)e1b[(csr[k] >> 16) * HID + j];
    float mean = ((s0 + s1) + (s2 + s3) + (s4 + s5) + (s6 + s7)) / fmaxf((float)deg, 1.0f);
    float h = fmaxf(mean + b1[j] + e1r[x_ids[i] * HID + j], 0.0f);
    int o = i * HID + j;
    h1[o] = h;
    h1b[o] = __float2bfloat16(h);
}

// ---------------- layer 2 aggregation only: mean2 = mean of h1b rows ----------------
__global__ __launch_bounds__(256) void agg2_mean_kernel(
        const __hip_bfloat16* __restrict__ h1b, const int* __restrict__ csr,
        const int* __restrict__ deg_arr, float* __restrict__ mean2) {
    int id = blockIdx.x * blockDim.x + threadIdx.x;
    int i = __builtin_amdgcn_readfirstlane(id >> 6);
    int j = threadIdx.x & 63;
    int s = i * MAXDEG;
    int deg = deg_arr[i];
    int e = s + deg;
    float s0 = 0.f, s1 = 0.f, s2 = 0.f, s3 = 0.f;
    float s4 = 0.f, s5 = 0.f, s6 = 0.f, s7 = 0.f;
    int k = s;
    for (; k + 8 <= e; k += 8) {
        int n0 = csr[k]     & 0xFFFF, n1 = csr[k + 1] & 0xFFFF;
        int n2 = csr[k + 2] & 0xFFFF, n3 = csr[k + 3] & 0xFFFF;
        int n4 = csr[k + 4] & 0xFFFF, n5 = csr[k + 5] & 0xFFFF;
        int n6 = csr[k + 6] & 0xFFFF, n7 = csr[k + 7] & 0xFFFF;
        s0 += (float)h1b[n0 * HID + j];
        s1 += (float)h1b[n1 * HID + j];
        s2 += (float)h1b[n2 * HID + j];
        s3 += (float)h1b[n3 * HID + j];
        s4 += (float)h1b[n4 * HID + j];
        s5 += (float)h1b[n5 * HID + j];
        s6 += (float)h1b[n6 * HID + j];
        s7 += (float)h1b[n7 * HID + j];
    }
    for (; k < e; ++k) s0 += (float)h1b[(csr[k] & 0xFFFF) * HID + j];
    float mean = ((s0 + s1) + (s2 + s3) + (s4 + s5) + (s6 + s7)) / fmaxf((float)deg, 1.0f);
    mean2[i * HID + j] = mean;
}

// ---------------- layer 2 linear + relu + pool: weights in VGPRs ----------------
__global__ __launch_bounds__(256) void lin2_pool_kernel(
        const float* __restrict__ mean2, const float* __restrict__ h1,
        const float* __restrict__ w2l, const float* __restrict__ b2,
        const float* __restrict__ w2r, const int* __restrict__ batch,
        float* __restrict__ gsum) {
    int lane = threadIdx.x & 63;
    int wv = (blockIdx.x * blockDim.x + threadIdx.x) >> 6;   // global wave id
    int i0 = wv * L2P_CHUNK;
    int i1 = i0 + L2P_CHUNK; if (i1 > N_NODES) i1 = N_NODES;
    if (i0 >= N_NODES) return;
    float wl[HID], wr[HID];
    #pragma unroll
    for (int k = 0; k < HID; ++k) {
        wl[k] = w2l[k * HID + lane];
        wr[k] = w2r[k * HID + lane];
    }
    float bj = b2[lane];
    int curg = __builtin_amdgcn_readfirstlane(batch[i0]);
    float accp = 0.0f;
    float m = mean2[i0 * HID + lane];
    float h = h1[i0 * HID + lane];
    for (int i = i0; i < i1; ++i) {
        float mn = 0.f, hn = 0.f;
        if (i + 1 < i1) {                      // prefetch next rows
            mn = mean2[(i + 1) * HID + lane];
            hn = h1[(i + 1) * HID + lane];
        }
        int g = __builtin_amdgcn_readfirstlane(batch[i]);
        if (g != curg) {
            atomicAdd(&gsum[curg * HID + lane], accp);
            accp = 0.0f;
            curg = g;
        }
        float z = bj;
        #pragma unroll
        for (int k = 0; k < HID; ++k)
            z = fmaf(rdlane(m, k), wl[k], fmaf(rdlane(h, k), wr[k], z));
        accp += fmaxf(z, 0.0f);
        m = mn; h = hn;
    }
    atomicAdd(&gsum[curg * HID + lane], accp);
}

// ---------------- output: pool-normalize + final linear ----------------
__global__ void out_kernel(const float* __restrict__ gsum, const int* __restrict__ batch,
                           const float* __restrict__ w_out, const float* __restrict__ b_out,
                           float* __restrict__ out) {
    int id = blockIdx.x * blockDim.x + threadIdx.x;
    if (id >= N_GRAPHS * N_CLASS) return;
    int g = id >> 1, c = id & 1;
    int lo = 0, hi = N_NODES;
    while (lo < hi) { int mid = (lo + hi) >> 1; if (batch[mid] < g) lo = mid + 1; else hi = mid; }
    int first = lo;
    lo = 0; hi = N_NODES;
    while (lo < hi) { int mid = (lo + hi) >> 1; if (batch[mid] <= g) lo = mid + 1; else hi = mid; }
    float cnt = (float)(lo - first);
    float inv = 1.0f / fmaxf(cnt, 1.0f);
    float acc = b_out[c];
    #pragma unroll
    for (int j = 0; j < HID; ++j)
        acc = fmaf(gsum[g * HID + j] * inv, w_out[j * N_CLASS + c], acc);
    out[id] = acc;
}

// ---------------- launch ----------------

extern "C" void kernel_launch(void* const* d_in, const int* in_sizes, int n_in,
                              void* d_out, int out_size, void* d_ws, size_t ws_size,
                              hipStream_t stream) {
    const int*   x_ids = (const int*)d_in[0];
    const int*   edge  = (const int*)d_in[1];
    const int*   batch = (const int*)d_in[2];
    const float* embed = (const float*)d_in[3];
    const float* w1l   = (const float*)d_in[4];
    const float* b1    = (const float*)d_in[5];
    const float* w1r   = (const float*)d_in[6];
    const float* w2l   = (const float*)d_in[7];
    const float* b2    = (const float*)d_in[8];
    const float* w2r   = (const float*)d_in[9];
    const float* wout  = (const float*)d_in[10];
    const float* bout  = (const float*)d_in[11];
    const int* src = edge;
    const int* dst = edge + N_EDGES;
    float* out = (float*)d_out;

    char* ws = (char*)d_ws;
    size_t off = 0;
    auto alloc = [&](size_t bytes) -> void* {
        void* p = ws + off;
        off += (bytes + 255) & ~(size_t)255;
        return p;
    };
    float*           h1     = (float*)alloc((size_t)N_NODES * HID * 4);          // 12.8 MB
    __hip_bfloat16*  h1b    = (__hip_bfloat16*)alloc((size_t)N_NODES * HID * 2); // 6.4 MB
    float*           mean2  = (float*)alloc((size_t)N_NODES * HID * 4);          // 12.8 MB
    int*             csr    = (int*)alloc((size_t)N_NODES * MAXDEG * 4);         // 19.2 MB
    int*             cursor = (int*)alloc((size_t)N_NODES * 4);                  // 200 KB
    int*             hist   = (int*)alloc((size_t)NBUCK * SORT_BLOCKS * 4);      // 150 KB
    __hip_bfloat16*  e1b    = (__hip_bfloat16*)alloc((size_t)VOCAB * HID * 2);   // 128 KB
    float*           e1r    = (float*)alloc((size_t)VOCAB * HID * 4);            // 256 KB
    float*           gsum   = (float*)alloc((size_t)N_GRAPHS * HID * 4);         // 128 KB

    // ebuf (12.8 MB) aliases mean2: K3 writes / K4 reads it strictly before
    // agg2_mean_kernel produces mean2. Exact size match: 1.6M * 8B = 50000*64*4B.
    u64* ebuf = (u64*)mean2;

    hipMemsetAsync(gsum, 0, (size_t)N_GRAPHS * HID * 4, stream);

    const int B = 256;
    precompute_e1_kernel<<<(VOCAB * HID + B - 1) / B, B, 0, stream>>>(embed, w1l, w1r, e1b, e1r);

    hist_kernel<<<SORT_BLOCKS, B, 0, stream>>>(dst, hist);
    scan_hist_kernel<<<1, B, 0, stream>>>(hist);
    scatter_kernel<<<SORT_BLOCKS, B, 0, stream>>>(src, dst, x_ids, hist, ebuf);
    csr_bucket_kernel<<<NBUCK, B, 0, stream>>>(ebuf, hist, cursor, csr);

    agg1_lin1_kernel<<<N_NODES * HID / B, B, 0, stream>>>(x_ids, csr, cursor,
                                                          e1b, e1r, b1, h1, h1b);
    agg2_mean_kernel<<<N_NODES * HID / B, B, 0, stream>>>(h1b, csr, cursor, mean2);
    lin2_pool_kernel<<<L2P_BLOCKS, B, 0, stream>>>(mean2, h1, w2l, b2, w2r, batch, gsum);
    out_kernel<<<(N_GRAPHS * N_CLASS + B - 1) / B, B, 0, stream>>>(gsum, batch, wout, bout, out);
}

// Round 4
// 232.525 us; speedup vs baseline: 1.3926x; 1.3926x over previous
//
#include <hip/hip_runtime.h>
#include <hip/hip_bf16.h>

#define N_NODES 50000
#define N_EDGES 1600000
#define N_GRAPHS 512
#define VOCAB 1000
#define EMB 32
#define HID 64
#define N_CLASS 2

#define MAXDEG 96                      // Poisson(32) tail @96 ~ 4e-20/node

// ---- atomic-free CSR build (counting bucket-sort) ----
#define NVEC (N_EDGES / 4)             // 400000 int4 vectors
#define SORT_VPB 1024                  // vectors per block (256 thr x 4)
#define SORT_BLOCKS ((NVEC + SORT_VPB - 1) / SORT_VPB)   // 391
#define BSHIFT 8
#define BUCKET_NODES 256
#define NBUCK ((N_NODES + BUCKET_NODES - 1) / BUCKET_NODES)  // 196

#define L2P_BLOCKS 768                 // 3 blocks/CU co-resident
#define L2P_WAVES (L2P_BLOCKS * 4)     // 3072
#define L2P_CHUNK ((N_NODES + L2P_WAVES - 1) / L2P_WAVES)  // 17

typedef int iv4 __attribute__((ext_vector_type(4)));
typedef unsigned long long u64;

__device__ __forceinline__ float rdlane(float v, int k) {
    return __int_as_float(__builtin_amdgcn_readlane(__float_as_int(v), k));
}

// ---------------- K1: per-block bucket histogram (LDS atomics only) ----------------
__global__ __launch_bounds__(256) void hist_kernel(const int* __restrict__ dst,
                                                   int* __restrict__ hist) {
    __shared__ int lh[NBUCK];
    for (int b = threadIdx.x; b < NBUCK; b += 256) lh[b] = 0;
    __syncthreads();
    const iv4* dst4 = (const iv4*)dst;
    int vbase = blockIdx.x * SORT_VPB;
    #pragma unroll
    for (int t = 0; t < 4; ++t) {
        int v = vbase + t * 256 + threadIdx.x;
        if (v < NVEC) {
            iv4 d4 = __builtin_nontemporal_load(&dst4[v]);
            atomicAdd(&lh[d4.x >> BSHIFT], 1);
            atomicAdd(&lh[d4.y >> BSHIFT], 1);
            atomicAdd(&lh[d4.z >> BSHIFT], 1);
            atomicAdd(&lh[d4.w >> BSHIFT], 1);
        }
    }
    __syncthreads();
    for (int b = threadIdx.x; b < NBUCK; b += 256)
        hist[b * SORT_BLOCKS + blockIdx.x] = lh[b];
}

// ---------------- K2a: per-bucket exclusive scan over its SORT_BLOCKS counters ----------------
// one block per bucket (all parallel); bucket total -> btot[b]
__global__ __launch_bounds__(256) void scan_rows_kernel(int* __restrict__ hist,
                                                        int* __restrict__ btot) {
    int* row = hist + (size_t)blockIdx.x * SORT_BLOCKS;
    __shared__ int wsum[4];
    int tid = threadIdx.x, lane = tid & 63, w = tid >> 6;
    int carry = 0;
    for (int base = 0; base < SORT_BLOCKS; base += 256) {
        int idx = base + tid;
        int v = (idx < SORT_BLOCKS) ? row[idx] : 0;
        int inc = v;
        #pragma unroll
        for (int off = 1; off < 64; off <<= 1) {
            int n = __shfl_up(inc, off, 64);
            if (lane >= off) inc += n;
        }
        if (lane == 63) wsum[w] = inc;
        __syncthreads();
        int woff = 0;
        #pragma unroll
        for (int k = 0; k < 4; ++k) if (k < w) woff += wsum[k];
        if (idx < SORT_BLOCKS) row[idx] = carry + woff + inc - v;
        carry += wsum[0] + wsum[1] + wsum[2] + wsum[3];
        __syncthreads();
    }
    if (tid == 0) btot[blockIdx.x] = carry;
}

// ---------------- K2b: exclusive scan of NBUCK bucket totals -> boff[NBUCK+1] ----------------
__global__ __launch_bounds__(256) void scan_btot_kernel(const int* __restrict__ btot,
                                                        int* __restrict__ boff) {
    __shared__ int wsum[4];
    int tid = threadIdx.x, lane = tid & 63, w = tid >> 6;
    int v = (tid < NBUCK) ? btot[tid] : 0;
    int inc = v;
    #pragma unroll
    for (int off = 1; off < 64; off <<= 1) {
        int n = __shfl_up(inc, off, 64);
        if (lane >= off) inc += n;
    }
    if (lane == 63) wsum[w] = inc;
    __syncthreads();
    int woff = 0;
    #pragma unroll
    for (int k = 0; k < 4; ++k) if (k < w) woff += wsum[k];
    if (tid < NBUCK) boff[tid] = woff + inc - v;
    if (tid == 0) boff[NBUCK] = wsum[0] + wsum[1] + wsum[2] + wsum[3];
}

// ---------------- K3: scatter edges into dense bucket-grouped buffer ----------------
// ebuf[pos] = (dst << 32) | (cls << 16) | src  ; pos = boff[b] + within-bucket offset
__global__ __launch_bounds__(256) void scatter_kernel(const int* __restrict__ src,
        const int* __restrict__ dst, const int* __restrict__ x_ids,
        const int* __restrict__ hist, const int* __restrict__ boff,
        u64* __restrict__ ebuf) {
    __shared__ int lbase[NBUCK];
    for (int b = threadIdx.x; b < NBUCK; b += 256)
        lbase[b] = hist[b * SORT_BLOCKS + blockIdx.x] + boff[b];
    __syncthreads();
    const iv4* dst4 = (const iv4*)dst;
    const iv4* src4 = (const iv4*)src;
    int vbase = blockIdx.x * SORT_VPB;
    #pragma unroll
    for (int t = 0; t < 4; ++t) {
        int v = vbase + t * 256 + threadIdx.x;
        if (v < NVEC) {
            iv4 d4 = __builtin_nontemporal_load(&dst4[v]);
            iv4 s4 = __builtin_nontemporal_load(&src4[v]);
            // phase 1: payload gathers (independent)
            int pay0 = (x_ids[s4.x] << 16) | s4.x;
            int pay1 = (x_ids[s4.y] << 16) | s4.y;
            int pay2 = (x_ids[s4.z] << 16) | s4.z;
            int pay3 = (x_ids[s4.w] << 16) | s4.w;
            // phase 2: LDS slot allocation (fast, per-CU)
            int p0 = atomicAdd(&lbase[d4.x >> BSHIFT], 1);
            int p1 = atomicAdd(&lbase[d4.y >> BSHIFT], 1);
            int p2 = atomicAdd(&lbase[d4.z >> BSHIFT], 1);
            int p3 = atomicAdd(&lbase[d4.w >> BSHIFT], 1);
            // phase 3: clustered 8B stores (bucket regions advance monotonically)
            ebuf[p0] = ((u64)(unsigned)d4.x << 32) | (unsigned)pay0;
            ebuf[p1] = ((u64)(unsigned)d4.y << 32) | (unsigned)pay1;
            ebuf[p2] = ((u64)(unsigned)d4.z << 32) | (unsigned)pay2;
            ebuf[p3] = ((u64)(unsigned)d4.w << 32) | (unsigned)pay3;
        }
    }
}

// ---------------- K4: per-bucket CSR build (LDS cursors, L2-local stores) ----------------
__global__ __launch_bounds__(256) void csr_bucket_kernel(const u64* __restrict__ ebuf,
        const int* __restrict__ boff, int* __restrict__ cursor, int* __restrict__ csr) {
    int b = blockIdx.x;
    __shared__ int cur[BUCKET_NODES];
    for (int r = threadIdx.x; r < BUCKET_NODES; r += 256) cur[r] = 0;
    __syncthreads();
    int base = boff[b];
    int end  = boff[b + 1];
    int node0 = b << BSHIFT;
    for (int i = base + threadIdx.x; i < end; i += 256) {
        u64 e = ebuf[i];                       // coalesced read
        int d = (int)(e >> 32);
        int pay = (int)(e & 0xffffffffu);
        int pos = atomicAdd(&cur[d - node0], 1);   // LDS atomic
        csr[d * MAXDEG + pos] = pay;               // store within 98KB slab
    }
    __syncthreads();
    for (int r = threadIdx.x; r < BUCKET_NODES; r += 256) {
        int d = node0 + r;
        if (d < N_NODES) cursor[d] = cur[r];
    }
}

// ---------------- precompute folded layer-1 tables ----------------
// e1b = bf16(embed @ w1l)  (VOCAB x HID), e1r = embed @ w1r (fp32)
__global__ void precompute_e1_kernel(const float* __restrict__ embed,
                                     const float* __restrict__ w1l,
                                     const float* __restrict__ w1r,
                                     __hip_bfloat16* __restrict__ e1b,
                                     float* __restrict__ e1r) {
    int id = blockIdx.x * blockDim.x + threadIdx.x;
    if (id >= VOCAB * HID) return;
    int v = id >> 6, j = id & 63;
    float a = 0.0f, b = 0.0f;
    #pragma unroll
    for (int k = 0; k < EMB; ++k) {
        float ev = embed[v * EMB + k];
        a = fmaf(ev, w1l[k * HID + j], a);
        b = fmaf(ev, w1r[k * HID + j], b);
    }
    e1b[id] = __float2bfloat16(a);
    e1r[id] = b;
}

// ---------------- layer 1: agg (bf16 class-table gather) + linear + relu ----------------
__global__ __launch_bounds__(256) void agg1_lin1_kernel(
        const int* __restrict__ x_ids, const int* __restrict__ csr,
        const int* __restrict__ deg_arr, const __hip_bfloat16* __restrict__ e1b,
        const float* __restrict__ e1r, const float* __restrict__ b1,
        float* __restrict__ h1, __hip_bfloat16* __restrict__ h1b) {
    int id = blockIdx.x * blockDim.x + threadIdx.x;
    int i = __builtin_amdgcn_readfirstlane(id >> 6);
    int j = threadIdx.x & 63;
    int s = i * MAXDEG;
    int deg = deg_arr[i];
    int e = s + deg;
    float s0 = 0.f, s1 = 0.f, s2 = 0.f, s3 = 0.f;
    float s4 = 0.f, s5 = 0.f, s6 = 0.f, s7 = 0.f;
    int k = s;
    for (; k + 8 <= e; k += 8) {
        int c0 = csr[k]     >> 16, c1 = csr[k + 1] >> 16;
        int c2 = csr[k + 2] >> 16, c3 = csr[k + 3] >> 16;
        int c4 = csr[k + 4] >> 16, c5 = csr[k + 5] >> 16;
        int c6 = csr[k + 6] >> 16, c7 = csr[k + 7] >> 16;
        s0 += (float)e1b[c0 * HID + j];
        s1 += (float)e1b[c1 * HID + j];
        s2 += (float)e1b[c2 * HID + j];
        s3 += (float)e1b[c3 * HID + j];
        s4 += (float)e1b[c4 * HID + j];
        s5 += (float)e1b[c5 * HID + j];
        s6 += (float)e1b[c6 * HID + j];
        s7 += (float)e1b[c7 * HID + j];
    }
    for (; k < e; ++k) s0 += (float)e1b[(csr[k] >> 16) * HID + j];
    float mean = ((s0 + s1) + (s2 + s3) + (s4 + s5) + (s6 + s7)) / fmaxf((float)deg, 1.0f);
    float h = fmaxf(mean + b1[j] + e1r[x_ids[i] * HID + j], 0.0f);
    int o = i * HID + j;
    h1[o] = h;
    h1b[o] = __float2bfloat16(h);
}

// ---------------- layer 2 aggregation only: mean2 = mean of h1b rows ----------------
__global__ __launch_bounds__(256) void agg2_mean_kernel(
        const __hip_bfloat16* __restrict__ h1b, const int* __restrict__ csr,
        const int* __restrict__ deg_arr, float* __restrict__ mean2) {
    int id = blockIdx.x * blockDim.x + threadIdx.x;
    int i = __builtin_amdgcn_readfirstlane(id >> 6);
    int j = threadIdx.x & 63;
    int s = i * MAXDEG;
    int deg = deg_arr[i];
    int e = s + deg;
    float s0 = 0.f, s1 = 0.f, s2 = 0.f, s3 = 0.f;
    float s4 = 0.f, s5 = 0.f, s6 = 0.f, s7 = 0.f;
    int k = s;
    for (; k + 8 <= e; k += 8) {
        int n0 = csr[k]     & 0xFFFF, n1 = csr[k + 1] & 0xFFFF;
        int n2 = csr[k + 2] & 0xFFFF, n3 = csr[k + 3] & 0xFFFF;
        int n4 = csr[k + 4] & 0xFFFF, n5 = csr[k + 5] & 0xFFFF;
        int n6 = csr[k + 6] & 0xFFFF, n7 = csr[k + 7] & 0xFFFF;
        s0 += (float)h1b[n0 * HID + j];
        s1 += (float)h1b[n1 * HID + j];
        s2 += (float)h1b[n2 * HID + j];
        s3 += (float)h1b[n3 * HID + j];
        s4 += (float)h1b[n4 * HID + j];
        s5 += (float)h1b[n5 * HID + j];
        s6 += (float)h1b[n6 * HID + j];
        s7 += (float)h1b[n7 * HID + j];
    }
    for (; k < e; ++k) s0 += (float)h1b[(csr[k] & 0xFFFF) * HID + j];
    float mean = ((s0 + s1) + (s2 + s3) + (s4 + s5) + (s6 + s7)) / fmaxf((float)deg, 1.0f);
    mean2[i * HID + j] = mean;
}

// ---------------- layer 2 linear + relu + pool: weights in VGPRs ----------------
__global__ __launch_bounds__(256) void lin2_pool_kernel(
        const float* __restrict__ mean2, const float* __restrict__ h1,
        const float* __restrict__ w2l, const float* __restrict__ b2,
        const float* __restrict__ w2r, const int* __restrict__ batch,
        float* __restrict__ gsum) {
    int lane = threadIdx.x & 63;
    int wv = (blockIdx.x * blockDim.x + threadIdx.x) >> 6;   // global wave id
    int i0 = wv * L2P_CHUNK;
    int i1 = i0 + L2P_CHUNK; if (i1 > N_NODES) i1 = N_NODES;
    if (i0 >= N_NODES) return;
    float wl[HID], wr[HID];
    #pragma unroll
    for (int k = 0; k < HID; ++k) {
        wl[k] = w2l[k * HID + lane];
        wr[k] = w2r[k * HID + lane];
    }
    float bj = b2[lane];
    int curg = __builtin_amdgcn_readfirstlane(batch[i0]);
    float accp = 0.0f;
    float m = mean2[i0 * HID + lane];
    float h = h1[i0 * HID + lane];
    for (int i = i0; i < i1; ++i) {
        float mn = 0.f, hn = 0.f;
        if (i + 1 < i1) {                      // prefetch next rows
            mn = mean2[(i + 1) * HID + lane];
            hn = h1[(i + 1) * HID + lane];
        }
        int g = __builtin_amdgcn_readfirstlane(batch[i]);
        if (g != curg) {
            atomicAdd(&gsum[curg * HID + lane], accp);
            accp = 0.0f;
            curg = g;
        }
        float z = bj;
        #pragma unroll
        for (int k = 0; k < HID; ++k)
            z = fmaf(rdlane(m, k), wl[k], fmaf(rdlane(h, k), wr[k], z));
        accp += fmaxf(z, 0.0f);
        m = mn; h = hn;
    }
    atomicAdd(&gsum[curg * HID + lane], accp);
}

// ---------------- output: pool-normalize + final linear ----------------
__global__ void out_kernel(const float* __restrict__ gsum, const int* __restrict__ batch,
                           const float* __restrict__ w_out, const float* __restrict__ b_out,
                           float* __restrict__ out) {
    int id = blockIdx.x * blockDim.x + threadIdx.x;
    if (id >= N_GRAPHS * N_CLASS) return;
    int g = id >> 1, c = id & 1;
    int lo = 0, hi = N_NODES;
    while (lo < hi) { int mid = (lo + hi) >> 1; if (batch[mid] < g) lo = mid + 1; else hi = mid; }
    int first = lo;
    lo = 0; hi = N_NODES;
    while (lo < hi) { int mid = (lo + hi) >> 1; if (batch[mid] <= g) lo = mid + 1; else hi = mid; }
    float cnt = (float)(lo - first);
    float inv = 1.0f / fmaxf(cnt, 1.0f);
    float acc = b_out[c];
    #pragma unroll
    for (int j = 0; j < HID; ++j)
        acc = fmaf(gsum[g * HID + j] * inv, w_out[j * N_CLASS + c], acc);
    out[id] = acc;
}

// ---------------- launch ----------------

extern "C" void kernel_launch(void* const* d_in, const int* in_sizes, int n_in,
                              void* d_out, int out_size, void* d_ws, size_t ws_size,
                              hipStream_t stream) {
    const int*   x_ids = (const int*)d_in[0];
    const int*   edge  = (const int*)d_in[1];
    const int*   batch = (const int*)d_in[2];
    const float* embed = (const float*)d_in[3];
    const float* w1l   = (const float*)d_in[4];
    const float* b1    = (const float*)d_in[5];
    const float* w1r   = (const float*)d_in[6];
    const float* w2l   = (const float*)d_in[7];
    const float* b2    = (const float*)d_in[8];
    const float* w2r   = (const float*)d_in[9];
    const float* wout  = (const float*)d_in[10];
    const float* bout  = (const float*)d_in[11];
    const int* src = edge;
    const int* dst = edge + N_EDGES;
    float* out = (float*)d_out;

    char* ws = (char*)d_ws;
    size_t off = 0;
    auto alloc = [&](size_t bytes) -> void* {
        void* p = ws + off;
        off += (bytes + 255) & ~(size_t)255;
        return p;
    };
    float*           h1     = (float*)alloc((size_t)N_NODES * HID * 4);          // 12.8 MB
    __hip_bfloat16*  h1b    = (__hip_bfloat16*)alloc((size_t)N_NODES * HID * 2); // 6.4 MB
    float*           mean2  = (float*)alloc((size_t)N_NODES * HID * 4);          // 12.8 MB
    int*             csr    = (int*)alloc((size_t)N_NODES * MAXDEG * 4);         // 19.2 MB
    int*             cursor = (int*)alloc((size_t)N_NODES * 4);                  // 200 KB
    int*             hist   = (int*)alloc((size_t)NBUCK * SORT_BLOCKS * 4);      // 307 KB
    int*             btot   = (int*)alloc((size_t)NBUCK * 4);
    int*             boff   = (int*)alloc((size_t)(NBUCK + 1) * 4);
    __hip_bfloat16*  e1b    = (__hip_bfloat16*)alloc((size_t)VOCAB * HID * 2);   // 128 KB
    float*           e1r    = (float*)alloc((size_t)VOCAB * HID * 4);            // 256 KB
    float*           gsum   = (float*)alloc((size_t)N_GRAPHS * HID * 4);         // 128 KB

    // ebuf (12.8 MB) aliases mean2: K3 writes / K4 reads it strictly before
    // agg2_mean_kernel produces mean2. Exact size match: 1.6M * 8B = 50000*64*4B.
    u64* ebuf = (u64*)mean2;

    hipMemsetAsync(gsum, 0, (size_t)N_GRAPHS * HID * 4, stream);

    const int B = 256;
    precompute_e1_kernel<<<(VOCAB * HID + B - 1) / B, B, 0, stream>>>(embed, w1l, w1r, e1b, e1r);

    hist_kernel<<<SORT_BLOCKS, B, 0, stream>>>(dst, hist);
    scan_rows_kernel<<<NBUCK, B, 0, stream>>>(hist, btot);
    scan_btot_kernel<<<1, B, 0, stream>>>(btot, boff);
    scatter_kernel<<<SORT_BLOCKS, B, 0, stream>>>(src, dst, x_ids, hist, boff, ebuf);
    csr_bucket_kernel<<<NBUCK, B, 0, stream>>>(ebuf, boff, cursor, csr);

    agg1_lin1_kernel<<<N_NODES * HID / B, B, 0, stream>>>(x_ids, csr, cursor,
                                                          e1b, e1r, b1, h1, h1b);
    agg2_mean_kernel<<<N_NODES * HID / B, B, 0, stream>>>(h1b, csr, cursor, mean2);
    lin2_pool_kernel<<<L2P_BLOCKS, B, 0, stream>>>(mean2, h1, w2l, b2, w2r, batch, gsum);
    out_kernel<<<(N_GRAPHS * N_CLASS + B - 1) / B, B, 0, stream>>>(gsum, batch, wout, bout, out);
}

// Round 5
// 223.151 us; speedup vs baseline: 1.4512x; 1.0420x over previous
//
#include <hip/hip_runtime.h>
#include <hip/hip_bf16.h>

#define N_NODES 50000
#define N_EDGES 1600000
#define N_GRAPHS 512
#define VOCAB 1000
#define EMB 32
#define HID 64
#define N_CLASS 2

#define MAXDEG 96                      // Poisson(32) tail @96 ~ 4e-20/node

// ---- atomic-free CSR build (counting bucket-sort) ----
#define NVEC (N_EDGES / 4)             // 400000 int4 vectors
#define SORT_VPB 1024                  // vectors per block (256 thr x 4)
#define SORT_BLOCKS ((NVEC + SORT_VPB - 1) / SORT_VPB)   // 391
#define BSHIFT 8
#define BUCKET_NODES 256
#define NBUCK ((N_NODES + BUCKET_NODES - 1) / BUCKET_NODES)  // 196

// ---- agg kernels: 8 lanes per node, 8 nodes per wave ----
#define AGG_THREADS (N_NODES * 8)
#define AGG_BLOCKS ((AGG_THREADS + 255) / 256)           // 1563

#define L2P_BLOCKS 768                 // 3 blocks/CU co-resident
#define L2P_WAVES (L2P_BLOCKS * 4)     // 3072
#define L2P_CHUNK ((N_NODES + L2P_WAVES - 1) / L2P_WAVES)  // 17

typedef int iv4 __attribute__((ext_vector_type(4)));
typedef unsigned short us;
typedef us usv8 __attribute__((ext_vector_type(8)));
typedef float fv4 __attribute__((ext_vector_type(4)));
typedef unsigned long long u64;

__device__ __forceinline__ float bf2f(us u) {
    union { unsigned int i; float f; } c;
    c.i = ((unsigned int)u) << 16;
    return c.f;
}
__device__ __forceinline__ us f2bf(float f) {
    union { __hip_bfloat16 b; us u; } c;
    c.b = __float2bfloat16(f);
    return c.u;
}
__device__ __forceinline__ float rdlane(float v, int k) {
    return __int_as_float(__builtin_amdgcn_readlane(__float_as_int(v), k));
}

// ---------------- K1: per-block bucket histogram (LDS atomics only) ----------------
__global__ __launch_bounds__(256) void hist_kernel(const int* __restrict__ dst,
                                                   int* __restrict__ hist) {
    __shared__ int lh[NBUCK];
    for (int b = threadIdx.x; b < NBUCK; b += 256) lh[b] = 0;
    __syncthreads();
    const iv4* dst4 = (const iv4*)dst;
    int vbase = blockIdx.x * SORT_VPB;
    #pragma unroll
    for (int t = 0; t < 4; ++t) {
        int v = vbase + t * 256 + threadIdx.x;
        if (v < NVEC) {
            iv4 d4 = __builtin_nontemporal_load(&dst4[v]);
            atomicAdd(&lh[d4.x >> BSHIFT], 1);
            atomicAdd(&lh[d4.y >> BSHIFT], 1);
            atomicAdd(&lh[d4.z >> BSHIFT], 1);
            atomicAdd(&lh[d4.w >> BSHIFT], 1);
        }
    }
    __syncthreads();
    for (int b = threadIdx.x; b < NBUCK; b += 256)
        hist[b * SORT_BLOCKS + blockIdx.x] = lh[b];
}

// ---------------- K2a: per-bucket exclusive scan over its SORT_BLOCKS counters ----------------
__global__ __launch_bounds__(256) void scan_rows_kernel(int* __restrict__ hist,
                                                        int* __restrict__ btot) {
    int* row = hist + (size_t)blockIdx.x * SORT_BLOCKS;
    __shared__ int wsum[4];
    int tid = threadIdx.x, lane = tid & 63, w = tid >> 6;
    int carry = 0;
    for (int base = 0; base < SORT_BLOCKS; base += 256) {
        int idx = base + tid;
        int v = (idx < SORT_BLOCKS) ? row[idx] : 0;
        int inc = v;
        #pragma unroll
        for (int off = 1; off < 64; off <<= 1) {
            int n = __shfl_up(inc, off, 64);
            if (lane >= off) inc += n;
        }
        if (lane == 63) wsum[w] = inc;
        __syncthreads();
        int woff = 0;
        #pragma unroll
        for (int k = 0; k < 4; ++k) if (k < w) woff += wsum[k];
        if (idx < SORT_BLOCKS) row[idx] = carry + woff + inc - v;
        carry += wsum[0] + wsum[1] + wsum[2] + wsum[3];
        __syncthreads();
    }
    if (tid == 0) btot[blockIdx.x] = carry;
}

// ---------------- K2b: exclusive scan of NBUCK bucket totals -> boff[NBUCK+1] ----------------
__global__ __launch_bounds__(256) void scan_btot_kernel(const int* __restrict__ btot,
                                                        int* __restrict__ boff) {
    __shared__ int wsum[4];
    int tid = threadIdx.x, lane = tid & 63, w = tid >> 6;
    int v = (tid < NBUCK) ? btot[tid] : 0;
    int inc = v;
    #pragma unroll
    for (int off = 1; off < 64; off <<= 1) {
        int n = __shfl_up(inc, off, 64);
        if (lane >= off) inc += n;
    }
    if (lane == 63) wsum[w] = inc;
    __syncthreads();
    int woff = 0;
    #pragma unroll
    for (int k = 0; k < 4; ++k) if (k < w) woff += wsum[k];
    if (tid < NBUCK) boff[tid] = woff + inc - v;
    if (tid == 0) boff[NBUCK] = wsum[0] + wsum[1] + wsum[2] + wsum[3];
}

// ---------------- K3: scatter edges into dense bucket-grouped buffer ----------------
__global__ __launch_bounds__(256) void scatter_kernel(const int* __restrict__ src,
        const int* __restrict__ dst, const int* __restrict__ x_ids,
        const int* __restrict__ hist, const int* __restrict__ boff,
        u64* __restrict__ ebuf) {
    __shared__ int lbase[NBUCK];
    for (int b = threadIdx.x; b < NBUCK; b += 256)
        lbase[b] = hist[b * SORT_BLOCKS + blockIdx.x] + boff[b];
    __syncthreads();
    const iv4* dst4 = (const iv4*)dst;
    const iv4* src4 = (const iv4*)src;
    int vbase = blockIdx.x * SORT_VPB;
    #pragma unroll
    for (int t = 0; t < 4; ++t) {
        int v = vbase + t * 256 + threadIdx.x;
        if (v < NVEC) {
            iv4 d4 = __builtin_nontemporal_load(&dst4[v]);
            iv4 s4 = __builtin_nontemporal_load(&src4[v]);
            int pay0 = (x_ids[s4.x] << 16) | s4.x;
            int pay1 = (x_ids[s4.y] << 16) | s4.y;
            int pay2 = (x_ids[s4.z] << 16) | s4.z;
            int pay3 = (x_ids[s4.w] << 16) | s4.w;
            int p0 = atomicAdd(&lbase[d4.x >> BSHIFT], 1);
            int p1 = atomicAdd(&lbase[d4.y >> BSHIFT], 1);
            int p2 = atomicAdd(&lbase[d4.z >> BSHIFT], 1);
            int p3 = atomicAdd(&lbase[d4.w >> BSHIFT], 1);
            ebuf[p0] = ((u64)(unsigned)d4.x << 32) | (unsigned)pay0;
            ebuf[p1] = ((u64)(unsigned)d4.y << 32) | (unsigned)pay1;
            ebuf[p2] = ((u64)(unsigned)d4.z << 32) | (unsigned)pay2;
            ebuf[p3] = ((u64)(unsigned)d4.w << 32) | (unsigned)pay3;
        }
    }
}

// ---------------- K4: per-bucket CSR build (LDS cursors, L2-local stores) ----------------
__global__ __launch_bounds__(256) void csr_bucket_kernel(const u64* __restrict__ ebuf,
        const int* __restrict__ boff, int* __restrict__ cursor, int* __restrict__ csr) {
    int b = blockIdx.x;
    __shared__ int cur[BUCKET_NODES];
    for (int r = threadIdx.x; r < BUCKET_NODES; r += 256) cur[r] = 0;
    __syncthreads();
    int base = boff[b];
    int end  = boff[b + 1];
    int node0 = b << BSHIFT;
    for (int i = base + threadIdx.x; i < end; i += 256) {
        u64 e = ebuf[i];
        int d = (int)(e >> 32);
        int pay = (int)(e & 0xffffffffu);
        int pos = atomicAdd(&cur[d - node0], 1);
        csr[d * MAXDEG + pos] = pay;
    }
    __syncthreads();
    for (int r = threadIdx.x; r < BUCKET_NODES; r += 256) {
        int d = node0 + r;
        if (d < N_NODES) cursor[d] = cur[r];
    }
}

// ---------------- precompute folded layer-1 tables ----------------
__global__ void precompute_e1_kernel(const float* __restrict__ embed,
                                     const float* __restrict__ w1l,
                                     const float* __restrict__ w1r,
                                     us* __restrict__ e1b,
                                     float* __restrict__ e1r) {
    int id = blockIdx.x * blockDim.x + threadIdx.x;
    if (id >= VOCAB * HID) return;
    int v = id >> 6, j = id & 63;
    float a = 0.0f, b = 0.0f;
    #pragma unroll
    for (int k = 0; k < EMB; ++k) {
        float ev = embed[v * EMB + k];
        a = fmaf(ev, w1l[k * HID + j], a);
        b = fmaf(ev, w1r[k * HID + j], b);
    }
    e1b[id] = f2bf(a);
    e1r[id] = b;
}

// ---------------- layer 1: agg + linear + relu, 8 lanes/node ----------------
// lane&7 = column octet (8 cols x 2B = ushort8), lane>>3 = node slot -> 8 nodes/wave.
// One gather instruction fetches 8 x 128B rows (1024B) vs 128B in the 1-node/wave layout.
__global__ __launch_bounds__(256) void agg1_lin1_kernel(
        const int* __restrict__ x_ids, const int* __restrict__ csr,
        const int* __restrict__ deg_arr, const us* __restrict__ e1b,
        const float* __restrict__ e1r, const float* __restrict__ b1,
        float* __restrict__ h1, us* __restrict__ h1b) {
    int tid = blockIdx.x * blockDim.x + threadIdx.x;
    int lane = threadIdx.x & 63;
    int g = lane >> 3, c8 = lane & 7;
    int node = (tid >> 6) * 8 + g;
    bool valid = node < N_NODES;
    int nclamp = valid ? node : 0;
    int deg = valid ? deg_arr[nclamp] : 0;
    const int* crow = csr + (size_t)nclamp * MAXDEG;
    float a0=0.f,a1=0.f,a2=0.f,a3=0.f,a4=0.f,a5=0.f,a6=0.f,a7=0.f;
    for (int k = 0; k < deg; k += 4) {
        iv4 cv = *(const iv4*)(crow + k);      // 16B idx batch, broadcast within group
        #define GATH1(CVAL, T)                                                   \
        if (k + (T) < deg) {                                                     \
            int cls = (CVAL) >> 16;                                              \
            usv8 r = *(const usv8*)(e1b + cls * HID + c8 * 8);                   \
            a0 += bf2f(r[0]); a1 += bf2f(r[1]); a2 += bf2f(r[2]); a3 += bf2f(r[3]); \
            a4 += bf2f(r[4]); a5 += bf2f(r[5]); a6 += bf2f(r[6]); a7 += bf2f(r[7]); \
        }
        GATH1(cv.x, 0) GATH1(cv.y, 1) GATH1(cv.z, 2) GATH1(cv.w, 3)
        #undef GATH1
    }
    if (!valid) return;
    float inv = 1.0f / fmaxf((float)deg, 1.0f);
    int xid = x_ids[nclamp];
    const fv4* er = (const fv4*)(e1r + xid * HID + c8 * 8);
    fv4 e0 = er[0], e1v = er[1];
    const fv4* bb = (const fv4*)(b1 + c8 * 8);
    fv4 b0 = bb[0], b1v = bb[1];
    fv4 h0, h1v;
    h0.x = fmaxf(a0 * inv + b0.x + e0.x, 0.0f);
    h0.y = fmaxf(a1 * inv + b0.y + e0.y, 0.0f);
    h0.z = fmaxf(a2 * inv + b0.z + e0.z, 0.0f);
    h0.w = fmaxf(a3 * inv + b0.w + e0.w, 0.0f);
    h1v.x = fmaxf(a4 * inv + b1v.x + e1v.x, 0.0f);
    h1v.y = fmaxf(a5 * inv + b1v.y + e1v.y, 0.0f);
    h1v.z = fmaxf(a6 * inv + b1v.z + e1v.z, 0.0f);
    h1v.w = fmaxf(a7 * inv + b1v.w + e1v.w, 0.0f);
    int o = node * HID + c8 * 8;
    *(fv4*)(h1 + o) = h0;
    *(fv4*)(h1 + o + 4) = h1v;
    usv8 hb;
    hb[0] = f2bf(h0.x); hb[1] = f2bf(h0.y); hb[2] = f2bf(h0.z); hb[3] = f2bf(h0.w);
    hb[4] = f2bf(h1v.x); hb[5] = f2bf(h1v.y); hb[6] = f2bf(h1v.z); hb[7] = f2bf(h1v.w);
    *(usv8*)(h1b + o) = hb;
}

// ---------------- layer 2 aggregation only: mean2 = mean of h1b rows, 8 lanes/node ----------------
__global__ __launch_bounds__(256) void agg2_mean_kernel(
        const us* __restrict__ h1b, const int* __restrict__ csr,
        const int* __restrict__ deg_arr, float* __restrict__ mean2) {
    int tid = blockIdx.x * blockDim.x + threadIdx.x;
    int lane = threadIdx.x & 63;
    int g = lane >> 3, c8 = lane & 7;
    int node = (tid >> 6) * 8 + g;
    bool valid = node < N_NODES;
    int nclamp = valid ? node : 0;
    int deg = valid ? deg_arr[nclamp] : 0;
    const int* crow = csr + (size_t)nclamp * MAXDEG;
    float a0=0.f,a1=0.f,a2=0.f,a3=0.f,a4=0.f,a5=0.f,a6=0.f,a7=0.f;
    for (int k = 0; k < deg; k += 4) {
        iv4 cv = *(const iv4*)(crow + k);
        #define GATH2(CVAL, T)                                                   \
        if (k + (T) < deg) {                                                     \
            int nb = (CVAL) & 0xFFFF;                                            \
            usv8 r = *(const usv8*)(h1b + nb * HID + c8 * 8);                    \
            a0 += bf2f(r[0]); a1 += bf2f(r[1]); a2 += bf2f(r[2]); a3 += bf2f(r[3]); \
            a4 += bf2f(r[4]); a5 += bf2f(r[5]); a6 += bf2f(r[6]); a7 += bf2f(r[7]); \
        }
        GATH2(cv.x, 0) GATH2(cv.y, 1) GATH2(cv.z, 2) GATH2(cv.w, 3)
        #undef GATH2
    }
    if (!valid) return;
    float inv = 1.0f / fmaxf((float)deg, 1.0f);
    fv4 m0, m1;
    m0.x = a0 * inv; m0.y = a1 * inv; m0.z = a2 * inv; m0.w = a3 * inv;
    m1.x = a4 * inv; m1.y = a5 * inv; m1.z = a6 * inv; m1.w = a7 * inv;
    int o = node * HID + c8 * 8;
    *(fv4*)(mean2 + o) = m0;
    *(fv4*)(mean2 + o + 4) = m1;
}

// ---------------- layer 2 linear + relu + pool: weights in VGPRs ----------------
__global__ __launch_bounds__(256) void lin2_pool_kernel(
        const float* __restrict__ mean2, const float* __restrict__ h1,
        const float* __restrict__ w2l, const float* __restrict__ b2,
        const float* __restrict__ w2r, const int* __restrict__ batch,
        float* __restrict__ gsum) {
    int lane = threadIdx.x & 63;
    int wv = (blockIdx.x * blockDim.x + threadIdx.x) >> 6;   // global wave id
    int i0 = wv * L2P_CHUNK;
    int i1 = i0 + L2P_CHUNK; if (i1 > N_NODES) i1 = N_NODES;
    if (i0 >= N_NODES) return;
    float wl[HID], wr[HID];
    #pragma unroll
    for (int k = 0; k < HID; ++k) {
        wl[k] = w2l[k * HID + lane];
        wr[k] = w2r[k * HID + lane];
    }
    float bj = b2[lane];
    int curg = __builtin_amdgcn_readfirstlane(batch[i0]);
    float accp = 0.0f;
    float m = mean2[i0 * HID + lane];
    float h = h1[i0 * HID + lane];
    for (int i = i0; i < i1; ++i) {
        float mn = 0.f, hn = 0.f;
        if (i + 1 < i1) {                      // prefetch next rows
            mn = mean2[(i + 1) * HID + lane];
            hn = h1[(i + 1) * HID + lane];
        }
        int g = __builtin_amdgcn_readfirstlane(batch[i]);
        if (g != curg) {
            atomicAdd(&gsum[curg * HID + lane], accp);
            accp = 0.0f;
            curg = g;
        }
        float z = bj;
        #pragma unroll
        for (int k = 0; k < HID; ++k)
            z = fmaf(rdlane(m, k), wl[k], fmaf(rdlane(h, k), wr[k], z));
        accp += fmaxf(z, 0.0f);
        m = mn; h = hn;
    }
    atomicAdd(&gsum[curg * HID + lane], accp);
}

// ---------------- output: pool-normalize + final linear ----------------
__global__ void out_kernel(const float* __restrict__ gsum, const int* __restrict__ batch,
                           const float* __restrict__ w_out, const float* __restrict__ b_out,
                           float* __restrict__ out) {
    int id = blockIdx.x * blockDim.x + threadIdx.x;
    if (id >= N_GRAPHS * N_CLASS) return;
    int g = id >> 1, c = id & 1;
    int lo = 0, hi = N_NODES;
    while (lo < hi) { int mid = (lo + hi) >> 1; if (batch[mid] < g) lo = mid + 1; else hi = mid; }
    int first = lo;
    lo = 0; hi = N_NODES;
    while (lo < hi) { int mid = (lo + hi) >> 1; if (batch[mid] <= g) lo = mid + 1; else hi = mid; }
    float cnt = (float)(lo - first);
    float inv = 1.0f / fmaxf(cnt, 1.0f);
    float acc = b_out[c];
    #pragma unroll
    for (int j = 0; j < HID; ++j)
        acc = fmaf(gsum[g * HID + j] * inv, w_out[j * N_CLASS + c], acc);
    out[id] = acc;
}

// ---------------- launch ----------------

extern "C" void kernel_launch(void* const* d_in, const int* in_sizes, int n_in,
                              void* d_out, int out_size, void* d_ws, size_t ws_size,
                              hipStream_t stream) {
    const int*   x_ids = (const int*)d_in[0];
    const int*   edge  = (const int*)d_in[1];
    const int*   batch = (const int*)d_in[2];
    const float* embed = (const float*)d_in[3];
    const float* w1l   = (const float*)d_in[4];
    const float* b1    = (const float*)d_in[5];
    const float* w1r   = (const float*)d_in[6];
    const float* w2l   = (const float*)d_in[7];
    const float* b2    = (const float*)d_in[8];
    const float* w2r   = (const float*)d_in[9];
    const float* wout  = (const float*)d_in[10];
    const float* bout  = (const float*)d_in[11];
    const int* src = edge;
    const int* dst = edge + N_EDGES;
    float* out = (float*)d_out;

    char* ws = (char*)d_ws;
    size_t off = 0;
    auto alloc = [&](size_t bytes) -> void* {
        void* p = ws + off;
        off += (bytes + 255) & ~(size_t)255;
        return p;
    };
    float*  h1     = (float*)alloc((size_t)N_NODES * HID * 4);          // 12.8 MB
    us*     h1b    = (us*)alloc((size_t)N_NODES * HID * 2);             // 6.4 MB
    float*  mean2  = (float*)alloc((size_t)N_NODES * HID * 4);          // 12.8 MB
    int*    csr    = (int*)alloc((size_t)N_NODES * MAXDEG * 4);         // 19.2 MB
    int*    cursor = (int*)alloc((size_t)N_NODES * 4);                  // 200 KB
    int*    hist   = (int*)alloc((size_t)NBUCK * SORT_BLOCKS * 4);      // 307 KB
    int*    btot   = (int*)alloc((size_t)NBUCK * 4);
    int*    boff   = (int*)alloc((size_t)(NBUCK + 1) * 4);
    us*     e1b    = (us*)alloc((size_t)VOCAB * HID * 2);               // 128 KB
    float*  e1r    = (float*)alloc((size_t)VOCAB * HID * 4);            // 256 KB
    float*  gsum   = (float*)alloc((size_t)N_GRAPHS * HID * 4);         // 128 KB

    // ebuf (12.8 MB) aliases mean2: K3 writes / K4 reads it strictly before
    // agg2_mean_kernel produces mean2. Exact size match: 1.6M * 8B = 50000*64*4B.
    u64* ebuf = (u64*)mean2;

    hipMemsetAsync(gsum, 0, (size_t)N_GRAPHS * HID * 4, stream);

    const int B = 256;
    precompute_e1_kernel<<<(VOCAB * HID + B - 1) / B, B, 0, stream>>>(embed, w1l, w1r, e1b, e1r);

    hist_kernel<<<SORT_BLOCKS, B, 0, stream>>>(dst, hist);
    scan_rows_kernel<<<NBUCK, B, 0, stream>>>(hist, btot);
    scan_btot_kernel<<<1, B, 0, stream>>>(btot, boff);
    scatter_kernel<<<SORT_BLOCKS, B, 0, stream>>>(src, dst, x_ids, hist, boff, ebuf);
    csr_bucket_kernel<<<NBUCK, B, 0, stream>>>(ebuf, boff, cursor, csr);

    agg1_lin1_kernel<<<AGG_BLOCKS, B, 0, stream>>>(x_ids, csr, cursor,
                                                   e1b, e1r, b1, h1, h1b);
    agg2_mean_kernel<<<AGG_BLOCKS, B, 0, stream>>>(h1b, csr, cursor, mean2);
    lin2_pool_kernel<<<L2P_BLOCKS, B, 0, stream>>>(mean2, h1, w2l, b2, w2r, batch, gsum);
    out_kernel<<<(N_GRAPHS * N_CLASS + B - 1) / B, B, 0, stream>>>(gsum, batch, wout, bout, out);
}